// Round 3
// baseline (439.738 us; speedup 1.0000x reference)
//
#include <hip/hip_runtime.h>

// Problem constants (fixed by the reference).
#define NN 204800
#define BB 4096
#define FF 256

// K0: segment boundaries via binary search (segment_ids sorted).
__global__ void k_bounds(const int* __restrict__ seg, int* __restrict__ start){
    int g = blockIdx.x * blockDim.x + threadIdx.x;
    if (g > BB) return;
    int lo = 0, hi = NN;
    while (lo < hi){ int mid = (lo + hi) >> 1; if (seg[mid] < g) lo = mid + 1; else hi = mid; }
    start[g] = lo;
}

// K1: per-graph context logit c_g = b_logit + dot(Wl[0:F], relu(g_feats[g])). Wave per graph.
__global__ void k_ctx_logit(const float* __restrict__ gfe, const float* __restrict__ Wl,
                            const float* __restrict__ bl, float* __restrict__ c){
    int wave = threadIdx.x >> 6, lane = threadIdx.x & 63;
    int g = blockIdx.x * 4 + wave;
    float4 gv = *(const float4*)(gfe + (size_t)g * FF + lane * 4);
    float4 wv = *(const float4*)(Wl + lane * 4);
    float sum = wv.x * fmaxf(gv.x, 0.f) + wv.y * fmaxf(gv.y, 0.f)
              + wv.z * fmaxf(gv.z, 0.f) + wv.w * fmaxf(gv.w, 0.f);
    #pragma unroll
    for (int o = 32; o; o >>= 1) sum += __shfl_xor(sum, o);
    if (lane == 0) c[g] = sum + bl[0];
}

// K2: per-node logit z_n = leaky_relu(c[seg_n] + dot(Wl[F:2F], x_n)). Wave per node.
__global__ void k_node_logit(const float* __restrict__ x, const float* __restrict__ Wl,
                             const float* __restrict__ c, const int* __restrict__ seg,
                             float* __restrict__ z){
    int wave = threadIdx.x >> 6, lane = threadIdx.x & 63;
    int n = blockIdx.x * 4 + wave;
    float4 xv = *(const float4*)(x + (size_t)n * FF + lane * 4);
    float4 wv = *(const float4*)(Wl + FF + lane * 4);
    float sum = xv.x * wv.x + xv.y * wv.y + xv.z * wv.z + xv.w * wv.w;
    #pragma unroll
    for (int o = 32; o; o >>= 1) sum += __shfl_xor(sum, o);
    if (lane == 0){
        float t = c[seg[n]] + sum;
        z[n] = t >= 0.f ? t : 0.01f * t;
    }
}

// K3: per-graph softmax stats (max, 1/denom). Wave per graph.
__global__ void k_stats(const float* __restrict__ z, const int* __restrict__ start,
                        float* __restrict__ m, float* __restrict__ invd){
    int wave = threadIdx.x >> 6, lane = threadIdx.x & 63;
    int g = blockIdx.x * 4 + wave;
    if (g >= BB) return;
    int s0 = start[g], s1 = start[g + 1];
    float mx = -3.4e38f;
    for (int i = s0 + lane; i < s1; i += 64) mx = fmaxf(mx, z[i]);
    #pragma unroll
    for (int o = 32; o; o >>= 1) mx = fmaxf(mx, __shfl_xor(mx, o));
    float d = 0.f;
    for (int i = s0 + lane; i < s1; i += 64) d += expf(z[i] - mx);
    #pragma unroll
    for (int o = 32; o; o >>= 1) d += __shfl_xor(d, o);
    if (lane == 0){
        m[g] = mx;
        invd[g] = (s1 > s0) ? (1.f / d) : 0.f;
    }
}

// K4: weighted node sum s_g = sum_n softmax_w(n) * x_n. Block (256 thr) per graph; thread = feature.
__global__ void k_wsum(const float* __restrict__ x, const float* __restrict__ z,
                       const int* __restrict__ start, const float* __restrict__ m,
                       const float* __restrict__ invd, float* __restrict__ s){
    int g = blockIdx.x;
    int t = threadIdx.x;
    int s0 = start[g], s1 = start[g + 1];
    float mg = m[g], iv = invd[g];
    float acc = 0.f;
    for (int n = s0; n < s1; n++){
        float w = expf(z[n] - mg);
        acc += w * x[(size_t)n * FF + t];
    }
    s[(size_t)g * FF + t] = acc * iv;
}

// K5: tiled GEMM: C[M,N] = act(A[M,K] @ W[N,K]^T + bias), fp32.
// BM=BN=64, BK=16, 256 threads, 4x4 per thread. ACT: 0=none, 1=ELU.
// gate: bias only added for rows m with gate[m+1]>gate[m] (non-empty graphs).
template<int ACT>
__global__ __launch_bounds__(256) void k_gemm(const float* __restrict__ A,
        const float* __restrict__ W, const float* __restrict__ bias,
        float* __restrict__ C, int M, int N, int K, const int* __restrict__ gate){
    __shared__ __align__(16) float As[16][68];
    __shared__ __align__(16) float Ws[16][68];
    int tid = threadIdx.x;
    int m0 = blockIdx.x * 64, n0 = blockIdx.y * 64;
    int lr = tid >> 2;          // 0..63 load row
    int lk = (tid & 3) * 4;     // k quad
    int r = tid >> 4, cc = tid & 15;
    float acc[4][4] = {};
    for (int k0 = 0; k0 < K; k0 += 16){
        float4 av = *(const float4*)(A + (size_t)(m0 + lr) * K + k0 + lk);
        As[lk + 0][lr] = av.x; As[lk + 1][lr] = av.y;
        As[lk + 2][lr] = av.z; As[lk + 3][lr] = av.w;
        float4 wv = *(const float4*)(W + (size_t)(n0 + lr) * K + k0 + lk);
        Ws[lk + 0][lr] = wv.x; Ws[lk + 1][lr] = wv.y;
        Ws[lk + 2][lr] = wv.z; Ws[lk + 3][lr] = wv.w;
        __syncthreads();
        #pragma unroll
        for (int kk = 0; kk < 16; kk++){
            float4 a = *(const float4*)(&As[kk][r * 4]);
            float4 b = *(const float4*)(&Ws[kk][cc * 4]);
            float aa[4] = {a.x, a.y, a.z, a.w};
            float bb[4] = {b.x, b.y, b.z, b.w};
            #pragma unroll
            for (int i = 0; i < 4; i++)
                #pragma unroll
                for (int j = 0; j < 4; j++)
                    acc[i][j] += aa[i] * bb[j];
        }
        __syncthreads();
    }
    #pragma unroll
    for (int i = 0; i < 4; i++){
        int mrow = m0 + r * 4 + i;
        float bs = 1.f;
        if (gate) bs = (gate[mrow + 1] > gate[mrow]) ? 1.f : 0.f;
        int n = n0 + cc * 4;
        float o[4];
        #pragma unroll
        for (int j = 0; j < 4; j++){
            float v = acc[i][j] + bs * bias[n + j];
            if (ACT == 1) v = v > 0.f ? v : expm1f(v);
            o[j] = v;
        }
        *(float4*)(C + (size_t)mrow * N + n) = make_float4(o[0], o[1], o[2], o[3]);
    }
}

// K6: fused GRU GEMMs + elementwise cell. Per block: 64 graphs x 64 feats tile.
// ai[s] = ctx @ Wih[s*F..]^T, ah[s] = g_feats @ Whh[s*F..]^T (s = r,z,n slices),
// then h' = (1-z)*n + z*h in the epilogue, fp32 output.
__global__ __launch_bounds__(256) void k_gru_fused(
        const float* __restrict__ ctx, const float* __restrict__ gfe,
        const float* __restrict__ Wih, const float* __restrict__ Whh,
        const float* __restrict__ bih, const float* __restrict__ bhh,
        float* __restrict__ out){
    __shared__ __align__(16) float Ac[16][68];
    __shared__ __align__(16) float Ag[16][68];
    __shared__ __align__(16) float Wt[6][16][68];  // ih_r, ih_z, ih_n, hh_r, hh_z, hh_n
    int tid = threadIdx.x;
    int g0 = blockIdx.x * 64, f0 = blockIdx.y * 64;
    int lr = tid >> 2;
    int lk = (tid & 3) * 4;
    int r = tid >> 4, cc = tid & 15;
    float ai[3][4][4] = {};
    float ah[3][4][4] = {};
    for (int k0 = 0; k0 < FF; k0 += 16){
        float4 av = *(const float4*)(ctx + (size_t)(g0 + lr) * FF + k0 + lk);
        Ac[lk + 0][lr] = av.x; Ac[lk + 1][lr] = av.y;
        Ac[lk + 2][lr] = av.z; Ac[lk + 3][lr] = av.w;
        float4 gv = *(const float4*)(gfe + (size_t)(g0 + lr) * FF + k0 + lk);
        Ag[lk + 0][lr] = gv.x; Ag[lk + 1][lr] = gv.y;
        Ag[lk + 2][lr] = gv.z; Ag[lk + 3][lr] = gv.w;
        #pragma unroll
        for (int s = 0; s < 3; s++){
            float4 wv = *(const float4*)(Wih + (size_t)(s * FF + f0 + lr) * FF + k0 + lk);
            Wt[s][lk + 0][lr] = wv.x; Wt[s][lk + 1][lr] = wv.y;
            Wt[s][lk + 2][lr] = wv.z; Wt[s][lk + 3][lr] = wv.w;
            float4 hv = *(const float4*)(Whh + (size_t)(s * FF + f0 + lr) * FF + k0 + lk);
            Wt[3 + s][lk + 0][lr] = hv.x; Wt[3 + s][lk + 1][lr] = hv.y;
            Wt[3 + s][lk + 2][lr] = hv.z; Wt[3 + s][lk + 3][lr] = hv.w;
        }
        __syncthreads();
        #pragma unroll
        for (int kk = 0; kk < 16; kk++){
            float ac[4], ag[4];
            *(float4*)ac = *(const float4*)(&Ac[kk][r * 4]);
            *(float4*)ag = *(const float4*)(&Ag[kk][r * 4]);
            #pragma unroll
            for (int s = 0; s < 3; s++){
                float4 bi = *(const float4*)(&Wt[s][kk][cc * 4]);
                float4 bh = *(const float4*)(&Wt[3 + s][kk][cc * 4]);
                float bis[4] = {bi.x, bi.y, bi.z, bi.w};
                float bhs[4] = {bh.x, bh.y, bh.z, bh.w};
                #pragma unroll
                for (int i = 0; i < 4; i++)
                    #pragma unroll
                    for (int j = 0; j < 4; j++){
                        ai[s][i][j] += ac[i] * bis[j];
                        ah[s][i][j] += ag[i] * bhs[j];
                    }
            }
        }
        __syncthreads();
    }
    #pragma unroll
    for (int i = 0; i < 4; i++){
        int g = g0 + r * 4 + i;
        int fb = f0 + cc * 4;
        float4 hv = *(const float4*)(gfe + (size_t)g * FF + fb);
        float hvs[4] = {hv.x, hv.y, hv.z, hv.w};
        float o[4];
        #pragma unroll
        for (int j = 0; j < 4; j++){
            int f = fb + j;
            float ir  = ai[0][i][j] + bih[f];
            float iz  = ai[1][i][j] + bih[FF + f];
            float in_ = ai[2][i][j] + bih[2 * FF + f];
            float hr  = ah[0][i][j] + bhh[f];
            float hz  = ah[1][i][j] + bhh[FF + f];
            float hn  = ah[2][i][j] + bhh[2 * FF + f];
            float rg = 1.f / (1.f + expf(-(ir + hr)));
            float zg = 1.f / (1.f + expf(-(iz + hz)));
            float ng = tanhf(in_ + rg * hn);
            o[j] = (1.f - zg) * ng + zg * hvs[j];
        }
        *(float4*)(out + (size_t)g * FF + fb) = make_float4(o[0], o[1], o[2], o[3]);
    }
}

extern "C" void kernel_launch(void* const* d_in, const int* in_sizes, int n_in,
                              void* d_out, int out_size, void* d_ws, size_t ws_size,
                              hipStream_t stream){
    const float* node = (const float*)d_in[0];
    const float* gfe  = (const float*)d_in[1];
    const int*   seg  = (const int*)d_in[2];
    const float* Wl   = (const float*)d_in[3];
    const float* bl   = (const float*)d_in[4];
    const float* Wp   = (const float*)d_in[5];
    const float* bp   = (const float*)d_in[6];
    const float* Wih  = (const float*)d_in[7];
    const float* Whh  = (const float*)d_in[8];
    const float* bih  = (const float*)d_in[9];
    const float* bhh  = (const float*)d_in[10];
    float* out = (float*)d_out;

    // Workspace carve-up (~9.3 MB total).
    char* p = (char*)d_ws;
    auto alloc = [&](size_t bytes)->void*{
        void* r = (void*)p; p += (bytes + 255) & ~(size_t)255; return r;
    };
    int*   start = (int*)  alloc((BB + 1) * sizeof(int));
    float* c     = (float*)alloc(BB * sizeof(float));
    float* z     = (float*)alloc(NN * sizeof(float));
    float* mbuf  = (float*)alloc(BB * sizeof(float));
    float* invd  = (float*)alloc(BB * sizeof(float));
    float* s     = (float*)alloc((size_t)BB * FF * sizeof(float));
    float* ctx   = (float*)alloc((size_t)BB * FF * sizeof(float));

    k_bounds<<<(BB + 256) / 256, 256, 0, stream>>>(seg, start);
    k_ctx_logit<<<BB / 4, 256, 0, stream>>>(gfe, Wl, bl, c);
    k_node_logit<<<NN / 4, 256, 0, stream>>>(node, Wl, c, seg, z);
    k_stats<<<BB / 4, 256, 0, stream>>>(z, start, mbuf, invd);
    k_wsum<<<BB, 256, 0, stream>>>(node, z, start, mbuf, invd, s);
    // ctx = elu(s @ W_proj^T + gated b_proj)
    k_gemm<1><<<dim3(BB / 64, FF / 64), 256, 0, stream>>>(s, Wp, bp, ctx, BB, FF, FF, start);
    // fused GRU: out = GRUCell(ctx, g_feats)
    k_gru_fused<<<dim3(BB / 64, FF / 64), 256, 0, stream>>>(ctx, gfe, Wih, Whh, bih, bhh, out);
}

// Round 4
// 409.899 us; speedup vs baseline: 1.0728x; 1.0728x over previous
//
#include <hip/hip_runtime.h>

// Problem constants (fixed by the reference).
#define NN 204800
#define BB 4096
#define FF 256

typedef unsigned short u16;
typedef unsigned int u32;
typedef short bf16x8 __attribute__((ext_vector_type(8)));   // 8 bf16 (4 VGPRs)
typedef float f32x4  __attribute__((ext_vector_type(4)));   // MFMA accumulator

__device__ __forceinline__ u16 rne_bf16(float f){
    union { u32 v; float f; } t; t.f = f;
    u32 lsb = (t.v >> 16) & 1u;
    t.v += 0x7fffu + lsb;
    return (u16)(t.v >> 16);
}

// K0: fused prep — segment bounds (first 4097 threads) + fp32->bf16 conversion of
// g_feats, W_proj, W_ih, W_hh (grid-stride by construction: grid covers total count).
__global__ void k_prep(const float* __restrict__ gfe, const float* __restrict__ Wp,
                       const float* __restrict__ Wih, const float* __restrict__ Whh,
                       const int* __restrict__ seg, int* __restrict__ start,
                       u16* __restrict__ gfe_b, u16* __restrict__ Wp_b,
                       u16* __restrict__ Wih_b, u16* __restrict__ Whh_b){
    int i = blockIdx.x * 256 + threadIdx.x;
    if (i <= BB){
        int lo = 0, hi = NN;
        while (lo < hi){ int mid = (lo + hi) >> 1; if (seg[mid] < i) lo = mid + 1; else hi = mid; }
        start[i] = lo;
    }
    const int n_gfe = BB * FF;       // 1048576
    const int n_wp  = FF * FF;       // 65536
    const int n_w3  = 3 * FF * FF;   // 196608
    int j = i;
    if (j < n_gfe){ gfe_b[j] = rne_bf16(gfe[j]); return; }
    j -= n_gfe;
    if (j < n_wp){ Wp_b[j] = rne_bf16(Wp[j]); return; }
    j -= n_wp;
    if (j < n_w3){ Wih_b[j] = rne_bf16(Wih[j]); return; }
    j -= n_w3;
    if (j < n_w3){ Whh_b[j] = rne_bf16(Whh[j]); return; }
}
#define PREP_TOTAL (BB*FF + FF*FF + 2*3*FF*FF)   // 1507328

// K1: per-graph context logit c_g = b_logit + dot(Wl[0:F], relu(g_feats[g])). Wave per graph.
__global__ void k_ctx_logit(const float* __restrict__ gfe, const float* __restrict__ Wl,
                            const float* __restrict__ bl, float* __restrict__ c){
    int wave = threadIdx.x >> 6, lane = threadIdx.x & 63;
    int g = blockIdx.x * 4 + wave;
    float4 gv = *(const float4*)(gfe + (size_t)g * FF + lane * 4);
    float4 wv = *(const float4*)(Wl + lane * 4);
    float sum = wv.x * fmaxf(gv.x, 0.f) + wv.y * fmaxf(gv.y, 0.f)
              + wv.z * fmaxf(gv.z, 0.f) + wv.w * fmaxf(gv.w, 0.f);
    #pragma unroll
    for (int o = 32; o; o >>= 1) sum += __shfl_xor(sum, o);
    if (lane == 0) c[g] = sum + bl[0];
}

// K2: per-node logit z_n = leaky_relu(c[seg_n] + dot(Wl[F:2F], x_n)). Wave per node.
__global__ void k_node_logit(const float* __restrict__ x, const float* __restrict__ Wl,
                             const float* __restrict__ c, const int* __restrict__ seg,
                             float* __restrict__ z){
    int wave = threadIdx.x >> 6, lane = threadIdx.x & 63;
    int n = blockIdx.x * 4 + wave;
    float4 xv = *(const float4*)(x + (size_t)n * FF + lane * 4);
    float4 wv = *(const float4*)(Wl + FF + lane * 4);
    float sum = xv.x * wv.x + xv.y * wv.y + xv.z * wv.z + xv.w * wv.w;
    #pragma unroll
    for (int o = 32; o; o >>= 1) sum += __shfl_xor(sum, o);
    if (lane == 0){
        float t = c[seg[n]] + sum;
        z[n] = t >= 0.f ? t : 0.01f * t;
    }
}

// K3: per-graph softmax stats (max, 1/denom). Wave per graph.
__global__ void k_stats(const float* __restrict__ z, const int* __restrict__ start,
                        float* __restrict__ m, float* __restrict__ invd){
    int wave = threadIdx.x >> 6, lane = threadIdx.x & 63;
    int g = blockIdx.x * 4 + wave;
    if (g >= BB) return;
    int s0 = start[g], s1 = start[g + 1];
    float mx = -3.4e38f;
    for (int i = s0 + lane; i < s1; i += 64) mx = fmaxf(mx, z[i]);
    #pragma unroll
    for (int o = 32; o; o >>= 1) mx = fmaxf(mx, __shfl_xor(mx, o));
    float d = 0.f;
    for (int i = s0 + lane; i < s1; i += 64) d += expf(z[i] - mx);
    #pragma unroll
    for (int o = 32; o; o >>= 1) d += __shfl_xor(d, o);
    if (lane == 0){
        m[g] = mx;
        invd[g] = (s1 > s0) ? (1.f / d) : 0.f;
    }
}

// K4: weighted node sum s_g = sum_n softmax_w(n) * x_n -> bf16. Block per graph; thread = feature.
__global__ void k_wsum(const float* __restrict__ x, const float* __restrict__ z,
                       const int* __restrict__ start, const float* __restrict__ m,
                       const float* __restrict__ invd, u16* __restrict__ s_b){
    int g = blockIdx.x;
    int t = threadIdx.x;
    int s0 = start[g], s1 = start[g + 1];
    float mg = m[g], iv = invd[g];
    float acc = 0.f;
    for (int n = s0; n < s1; n++){
        float w = expf(z[n] - mg);
        acc += w * x[(size_t)n * FF + t];
    }
    s_b[(size_t)g * FF + t] = rne_bf16(acc * iv);
}

// K5: MFMA proj GEMM: ctx = ELU(s @ Wp^T + gate*bp), bf16 in, bf16 out, fp32 acc.
// Grid (BB/64, FF/64), 256 thr = 4 waves; wave = 16 graph rows x 64 feats.
// Fragment layouts (mfma_f32_16x16x32_bf16): A[m=l&15][k=q*8+j]; B-frag lane holds
// W[n=l&15][k=q*8+j] (B^T pattern); D[m=q*4+r][n=l&15].
__global__ __launch_bounds__(256) void k_proj_mfma(
        const u16* __restrict__ s_b, const u16* __restrict__ Wp_b,
        const float* __restrict__ bp, const int* __restrict__ gate,
        u16* __restrict__ ctx_b){
    int tid = threadIdx.x;
    int w = tid >> 6, l = tid & 63;
    int mn = l & 15, q = l >> 4;
    int m0 = blockIdx.x * 64 + w * 16;
    int f0 = blockIdx.y * 64;
    f32x4 acc[4] = {};
    const u16* arow = s_b + (size_t)(m0 + mn) * FF + q * 8;
    #pragma unroll
    for (int kb = 0; kb < 8; kb++){
        bf16x8 a = *(const bf16x8*)(arow + kb * 32);
        #pragma unroll
        for (int c = 0; c < 4; c++){
            bf16x8 b = *(const bf16x8*)(Wp_b + (size_t)(f0 + c * 16 + mn) * FF + kb * 32 + q * 8);
            acc[c] = __builtin_amdgcn_mfma_f32_16x16x32_bf16(a, b, acc[c], 0, 0, 0);
        }
    }
    #pragma unroll
    for (int c = 0; c < 4; c++){
        int f = f0 + c * 16 + mn;
        float bias = bp[f];
        #pragma unroll
        for (int r = 0; r < 4; r++){
            int g = m0 + q * 4 + r;
            float bs = (gate[g + 1] > gate[g]) ? 1.f : 0.f;
            float v = acc[c][r] + bs * bias;
            v = v > 0.f ? v : expm1f(v);
            ctx_b[(size_t)g * FF + f] = rne_bf16(v);
        }
    }
}

// K6: MFMA fused GRU: 6 GEMM tiles (ctx@Wih_r/z/n, gfe@Whh_r/z/n) + cell epilogue.
__global__ __launch_bounds__(256) void k_gru_mfma(
        const u16* __restrict__ ctx_b, const u16* __restrict__ gfe_b,
        const u16* __restrict__ Wih_b, const u16* __restrict__ Whh_b,
        const float* __restrict__ bih, const float* __restrict__ bhh,
        const float* __restrict__ gfe, float* __restrict__ out){
    int tid = threadIdx.x;
    int w = tid >> 6, l = tid & 63;
    int mn = l & 15, q = l >> 4;
    int g0 = blockIdx.x * 64 + w * 16;
    int f0 = blockIdx.y * 64;
    f32x4 ai[3][4] = {};
    f32x4 ah[3][4] = {};
    const u16* ac_row = ctx_b + (size_t)(g0 + mn) * FF + q * 8;
    const u16* ag_row = gfe_b + (size_t)(g0 + mn) * FF + q * 8;
    #pragma unroll
    for (int kb = 0; kb < 8; kb++){
        bf16x8 a_c = *(const bf16x8*)(ac_row + kb * 32);
        bf16x8 a_g = *(const bf16x8*)(ag_row + kb * 32);
        #pragma unroll
        for (int s = 0; s < 3; s++){
            #pragma unroll
            for (int c = 0; c < 4; c++){
                size_t woff = (size_t)(s * FF + f0 + c * 16 + mn) * FF + kb * 32 + q * 8;
                bf16x8 bi = *(const bf16x8*)(Wih_b + woff);
                ai[s][c] = __builtin_amdgcn_mfma_f32_16x16x32_bf16(a_c, bi, ai[s][c], 0, 0, 0);
                bf16x8 bh = *(const bf16x8*)(Whh_b + woff);
                ah[s][c] = __builtin_amdgcn_mfma_f32_16x16x32_bf16(a_g, bh, ah[s][c], 0, 0, 0);
            }
        }
    }
    #pragma unroll
    for (int c = 0; c < 4; c++){
        int f = f0 + c * 16 + mn;
        float bir = bih[f], biz = bih[FF + f], bin_ = bih[2 * FF + f];
        float bhr = bhh[f], bhz = bhh[FF + f], bhn = bhh[2 * FF + f];
        #pragma unroll
        for (int r = 0; r < 4; r++){
            int g = g0 + q * 4 + r;
            float rg = 1.f / (1.f + expf(-(ai[0][c][r] + bir + ah[0][c][r] + bhr)));
            float zg = 1.f / (1.f + expf(-(ai[1][c][r] + biz + ah[1][c][r] + bhz)));
            float ng = tanhf(ai[2][c][r] + bin_ + rg * (ah[2][c][r] + bhn));
            float h = gfe[(size_t)g * FF + f];
            out[(size_t)g * FF + f] = (1.f - zg) * ng + zg * h;
        }
    }
}

extern "C" void kernel_launch(void* const* d_in, const int* in_sizes, int n_in,
                              void* d_out, int out_size, void* d_ws, size_t ws_size,
                              hipStream_t stream){
    const float* node = (const float*)d_in[0];
    const float* gfe  = (const float*)d_in[1];
    const int*   seg  = (const int*)d_in[2];
    const float* Wl   = (const float*)d_in[3];
    const float* bl   = (const float*)d_in[4];
    const float* Wp   = (const float*)d_in[5];
    const float* bp   = (const float*)d_in[6];
    const float* Wih  = (const float*)d_in[7];
    const float* Whh  = (const float*)d_in[8];
    const float* bih  = (const float*)d_in[9];
    const float* bhh  = (const float*)d_in[10];
    float* out = (float*)d_out;

    // Workspace carve-up (~8 MB total).
    char* p = (char*)d_ws;
    auto alloc = [&](size_t bytes)->void*{
        void* r = (void*)p; p += (bytes + 255) & ~(size_t)255; return r;
    };
    int*   start = (int*)  alloc((BB + 1) * sizeof(int));
    float* c     = (float*)alloc(BB * sizeof(float));
    float* z     = (float*)alloc(NN * sizeof(float));
    float* mbuf  = (float*)alloc(BB * sizeof(float));
    float* invd  = (float*)alloc(BB * sizeof(float));
    u16*   s_b   = (u16*)  alloc((size_t)BB * FF * sizeof(u16));
    u16*   ctx_b = (u16*)  alloc((size_t)BB * FF * sizeof(u16));
    u16*   gfe_b = (u16*)  alloc((size_t)BB * FF * sizeof(u16));
    u16*   Wp_b  = (u16*)  alloc((size_t)FF * FF * sizeof(u16));
    u16*   Wih_b = (u16*)  alloc((size_t)3 * FF * FF * sizeof(u16));
    u16*   Whh_b = (u16*)  alloc((size_t)3 * FF * FF * sizeof(u16));

    k_prep<<<(PREP_TOTAL + 255) / 256, 256, 0, stream>>>(gfe, Wp, Wih, Whh, seg, start,
                                                         gfe_b, Wp_b, Wih_b, Whh_b);
    k_ctx_logit<<<BB / 4, 256, 0, stream>>>(gfe, Wl, bl, c);
    k_node_logit<<<NN / 4, 256, 0, stream>>>(node, Wl, c, seg, z);
    k_stats<<<BB / 4, 256, 0, stream>>>(z, start, mbuf, invd);
    k_wsum<<<BB, 256, 0, stream>>>(node, z, start, mbuf, invd, s_b);
    k_proj_mfma<<<dim3(BB / 64, FF / 64), 256, 0, stream>>>(s_b, Wp_b, bp, start, ctx_b);
    k_gru_mfma<<<dim3(BB / 64, FF / 64), 256, 0, stream>>>(ctx_b, gfe_b, Wih_b, Whh_b,
                                                           bih, bhh, gfe, out);
}

// Round 5
// 385.096 us; speedup vs baseline: 1.1419x; 1.0644x over previous
//
#include <hip/hip_runtime.h>

// Problem constants (fixed by the reference).
#define NN 204800
#define BB 4096
#define FF 256
#define CAP 64   // LDS-staged rows per graph (64 KB); overflow re-reads global (L2-warm)

typedef unsigned short u16;
typedef unsigned int u32;
typedef short bf16x8 __attribute__((ext_vector_type(8)));   // 8 bf16 (4 VGPRs)
typedef float f32x4  __attribute__((ext_vector_type(4)));   // MFMA accumulator

__device__ __forceinline__ u16 rne_bf16(float f){
    union { u32 v; float f; } t; t.f = f;
    u32 lsb = (t.v >> 16) & 1u;
    t.v += 0x7fffu + lsb;
    return (u16)(t.v >> 16);
}

// K0: fused prep — segment bounds (first 4097 threads) + fp32->bf16 conversion of
// g_feats, W_proj, W_ih, W_hh.
__global__ void k_prep(const float* __restrict__ gfe, const float* __restrict__ Wp,
                       const float* __restrict__ Wih, const float* __restrict__ Whh,
                       const int* __restrict__ seg, int* __restrict__ start,
                       u16* __restrict__ gfe_b, u16* __restrict__ Wp_b,
                       u16* __restrict__ Wih_b, u16* __restrict__ Whh_b){
    int i = blockIdx.x * 256 + threadIdx.x;
    if (i <= BB){
        int lo = 0, hi = NN;
        while (lo < hi){ int mid = (lo + hi) >> 1; if (seg[mid] < i) lo = mid + 1; else hi = mid; }
        start[i] = lo;
    }
    const int n_gfe = BB * FF;
    const int n_wp  = FF * FF;
    const int n_w3  = 3 * FF * FF;
    int j = i;
    if (j < n_gfe){ gfe_b[j] = rne_bf16(gfe[j]); return; }
    j -= n_gfe;
    if (j < n_wp){ Wp_b[j] = rne_bf16(Wp[j]); return; }
    j -= n_wp;
    if (j < n_w3){ Wih_b[j] = rne_bf16(Wih[j]); return; }
    j -= n_w3;
    if (j < n_w3){ Whh_b[j] = rne_bf16(Whh[j]); return; }
}
#define PREP_TOTAL (BB*FF + FF*FF + 2*3*FF*FF)   // 1507328

// K1: per-graph context logit c_g = b_logit + dot(Wl[0:F], relu(g_feats[g])). Wave per graph.
__global__ void k_ctx_logit(const float* __restrict__ gfe, const float* __restrict__ Wl,
                            const float* __restrict__ bl, float* __restrict__ c){
    int wave = threadIdx.x >> 6, lane = threadIdx.x & 63;
    int g = blockIdx.x * 4 + wave;
    float4 gv = *(const float4*)(gfe + (size_t)g * FF + lane * 4);
    float4 wv = *(const float4*)(Wl + lane * 4);
    float sum = wv.x * fmaxf(gv.x, 0.f) + wv.y * fmaxf(gv.y, 0.f)
              + wv.z * fmaxf(gv.z, 0.f) + wv.w * fmaxf(gv.w, 0.f);
    #pragma unroll
    for (int o = 32; o; o >>= 1) sum += __shfl_xor(sum, o);
    if (lane == 0) c[g] = sum + bl[0];
}

// K2: fused attention — ONE pass over node_feats per graph.
// Block (256 thr = 4 waves) per graph. Phase A: stream rows, stage to LDS (<=CAP),
// compute z per node (wave-reduce). Phase B: block max + denom, exp weights in LDS.
// Phase C: weighted feature sum from LDS -> bf16 s.
__global__ __launch_bounds__(256) void k_attn(
        const float* __restrict__ x, const float* __restrict__ Wl,
        const float* __restrict__ c, const int* __restrict__ start,
        u16* __restrict__ s_b){
    __shared__ __align__(16) float xs[CAP][FF];  // 64 KB
    __shared__ float zs[512];                    // z, then exp weights
    __shared__ float red[8];
    int g = blockIdx.x;
    int s0 = start[g], cnt = start[g + 1] - s0;
    int tid = threadIdx.x, wave = tid >> 6, lane = tid & 63;
    if (cnt == 0){                   // block-uniform: safe early exit
        s_b[(size_t)g * FF + tid] = 0;
        return;
    }
    float4 wv = *(const float4*)(Wl + FF + lane * 4);
    float cg = c[g];
    // Phase A (2x unrolled: two outstanding row loads per wave)
    int i = wave;
    for (; i + 4 < cnt; i += 8){
        float4 xv0 = *(const float4*)(x + (size_t)(s0 + i) * FF + lane * 4);
        float4 xv1 = *(const float4*)(x + (size_t)(s0 + i + 4) * FF + lane * 4);
        if (i < CAP) *(float4*)(&xs[i][lane * 4]) = xv0;
        if (i + 4 < CAP) *(float4*)(&xs[i + 4][lane * 4]) = xv1;
        float d0 = xv0.x * wv.x + xv0.y * wv.y + xv0.z * wv.z + xv0.w * wv.w;
        float d1 = xv1.x * wv.x + xv1.y * wv.y + xv1.z * wv.z + xv1.w * wv.w;
        #pragma unroll
        for (int o = 32; o; o >>= 1){ d0 += __shfl_xor(d0, o); d1 += __shfl_xor(d1, o); }
        if (lane == 0){
            float t0 = cg + d0; zs[i] = t0 >= 0.f ? t0 : 0.01f * t0;
            float t1 = cg + d1; zs[i + 4] = t1 >= 0.f ? t1 : 0.01f * t1;
        }
    }
    for (; i < cnt; i += 4){
        float4 xv = *(const float4*)(x + (size_t)(s0 + i) * FF + lane * 4);
        if (i < CAP) *(float4*)(&xs[i][lane * 4]) = xv;
        float d = xv.x * wv.x + xv.y * wv.y + xv.z * wv.z + xv.w * wv.w;
        #pragma unroll
        for (int o = 32; o; o >>= 1) d += __shfl_xor(d, o);
        if (lane == 0){
            float t = cg + d; zs[i] = t >= 0.f ? t : 0.01f * t;
        }
    }
    __syncthreads();
    // Phase B: block max
    float mx = -3.4e38f;
    for (int k = tid; k < cnt; k += 256) mx = fmaxf(mx, zs[k]);
    #pragma unroll
    for (int o = 32; o; o >>= 1) mx = fmaxf(mx, __shfl_xor(mx, o));
    if (lane == 0) red[wave] = mx;
    __syncthreads();
    mx = fmaxf(fmaxf(red[0], red[1]), fmaxf(red[2], red[3]));
    // denom; overwrite zs with exp weights (each k owned by exactly one thread)
    float dsum = 0.f;
    for (int k = tid; k < cnt; k += 256){
        float e = expf(zs[k] - mx);
        zs[k] = e;
        dsum += e;
    }
    #pragma unroll
    for (int o = 32; o; o >>= 1) dsum += __shfl_xor(dsum, o);
    if (lane == 0) red[4 + wave] = dsum;
    __syncthreads();
    float inv = 1.f / (red[4] + red[5] + red[6] + red[7]);
    // Phase C: weighted sum; thread = feature
    float acc = 0.f;
    int lim = cnt < CAP ? cnt : CAP;
    for (int k = 0; k < lim; k++) acc += zs[k] * xs[k][tid];
    for (int k = CAP; k < cnt; k++) acc += zs[k] * x[(size_t)(s0 + k) * FF + tid];
    s_b[(size_t)g * FF + tid] = rne_bf16(acc * inv);
}

// K3: MFMA proj GEMM: ctx = ELU(s @ Wp^T + gate*bp), bf16 in/out, fp32 acc.
__global__ __launch_bounds__(256) void k_proj_mfma(
        const u16* __restrict__ s_b, const u16* __restrict__ Wp_b,
        const float* __restrict__ bp, const int* __restrict__ gate,
        u16* __restrict__ ctx_b){
    int tid = threadIdx.x;
    int w = tid >> 6, l = tid & 63;
    int mn = l & 15, q = l >> 4;
    int m0 = blockIdx.x * 64 + w * 16;
    int f0 = blockIdx.y * 64;
    f32x4 acc[4] = {};
    const u16* arow = s_b + (size_t)(m0 + mn) * FF + q * 8;
    #pragma unroll
    for (int kb = 0; kb < 8; kb++){
        bf16x8 a = *(const bf16x8*)(arow + kb * 32);
        #pragma unroll
        for (int cc = 0; cc < 4; cc++){
            bf16x8 b = *(const bf16x8*)(Wp_b + (size_t)(f0 + cc * 16 + mn) * FF + kb * 32 + q * 8);
            acc[cc] = __builtin_amdgcn_mfma_f32_16x16x32_bf16(a, b, acc[cc], 0, 0, 0);
        }
    }
    #pragma unroll
    for (int cc = 0; cc < 4; cc++){
        int f = f0 + cc * 16 + mn;
        float bias = bp[f];
        #pragma unroll
        for (int r = 0; r < 4; r++){
            int g = m0 + q * 4 + r;
            float bs = (gate[g + 1] > gate[g]) ? 1.f : 0.f;
            float v = acc[cc][r] + bs * bias;
            v = v > 0.f ? v : expm1f(v);
            ctx_b[(size_t)g * FF + f] = rne_bf16(v);
        }
    }
}

// K4: MFMA fused GRU: 6 GEMM tiles (ctx@Wih_r/z/n, gfe@Whh_r/z/n) + cell epilogue.
__global__ __launch_bounds__(256) void k_gru_mfma(
        const u16* __restrict__ ctx_b, const u16* __restrict__ gfe_b,
        const u16* __restrict__ Wih_b, const u16* __restrict__ Whh_b,
        const float* __restrict__ bih, const float* __restrict__ bhh,
        const float* __restrict__ gfe, float* __restrict__ out){
    int tid = threadIdx.x;
    int w = tid >> 6, l = tid & 63;
    int mn = l & 15, q = l >> 4;
    int g0 = blockIdx.x * 64 + w * 16;
    int f0 = blockIdx.y * 64;
    f32x4 ai[3][4] = {};
    f32x4 ah[3][4] = {};
    const u16* ac_row = ctx_b + (size_t)(g0 + mn) * FF + q * 8;
    const u16* ag_row = gfe_b + (size_t)(g0 + mn) * FF + q * 8;
    #pragma unroll
    for (int kb = 0; kb < 8; kb++){
        bf16x8 a_c = *(const bf16x8*)(ac_row + kb * 32);
        bf16x8 a_g = *(const bf16x8*)(ag_row + kb * 32);
        #pragma unroll
        for (int s = 0; s < 3; s++){
            #pragma unroll
            for (int cc = 0; cc < 4; cc++){
                size_t woff = (size_t)(s * FF + f0 + cc * 16 + mn) * FF + kb * 32 + q * 8;
                bf16x8 bi = *(const bf16x8*)(Wih_b + woff);
                ai[s][cc] = __builtin_amdgcn_mfma_f32_16x16x32_bf16(a_c, bi, ai[s][cc], 0, 0, 0);
                bf16x8 bh = *(const bf16x8*)(Whh_b + woff);
                ah[s][cc] = __builtin_amdgcn_mfma_f32_16x16x32_bf16(a_g, bh, ah[s][cc], 0, 0, 0);
            }
        }
    }
    #pragma unroll
    for (int cc = 0; cc < 4; cc++){
        int f = f0 + cc * 16 + mn;
        float bir = bih[f], biz = bih[FF + f], bin_ = bih[2 * FF + f];
        float bhr = bhh[f], bhz = bhh[FF + f], bhn = bhh[2 * FF + f];
        #pragma unroll
        for (int r = 0; r < 4; r++){
            int g = g0 + q * 4 + r;
            float rg = 1.f / (1.f + expf(-(ai[0][cc][r] + bir + ah[0][cc][r] + bhr)));
            float zg = 1.f / (1.f + expf(-(ai[1][cc][r] + biz + ah[1][cc][r] + bhz)));
            float ng = tanhf(ai[2][cc][r] + bin_ + rg * (ah[2][cc][r] + bhn));
            float h = gfe[(size_t)g * FF + f];
            out[(size_t)g * FF + f] = (1.f - zg) * ng + zg * h;
        }
    }
}

extern "C" void kernel_launch(void* const* d_in, const int* in_sizes, int n_in,
                              void* d_out, int out_size, void* d_ws, size_t ws_size,
                              hipStream_t stream){
    const float* node = (const float*)d_in[0];
    const float* gfe  = (const float*)d_in[1];
    const int*   seg  = (const int*)d_in[2];
    const float* Wl   = (const float*)d_in[3];
    const float* bl   = (const float*)d_in[4];
    const float* Wp   = (const float*)d_in[5];
    const float* bp   = (const float*)d_in[6];
    const float* Wih  = (const float*)d_in[7];
    const float* Whh  = (const float*)d_in[8];
    const float* bih  = (const float*)d_in[9];
    const float* bhh  = (const float*)d_in[10];
    float* out = (float*)d_out;

    // Workspace carve-up (~7 MB total).
    char* p = (char*)d_ws;
    auto alloc = [&](size_t bytes)->void*{
        void* r = (void*)p; p += (bytes + 255) & ~(size_t)255; return r;
    };
    int*   start = (int*)  alloc((BB + 1) * sizeof(int));
    float* c     = (float*)alloc(BB * sizeof(float));
    u16*   s_b   = (u16*)  alloc((size_t)BB * FF * sizeof(u16));
    u16*   ctx_b = (u16*)  alloc((size_t)BB * FF * sizeof(u16));
    u16*   gfe_b = (u16*)  alloc((size_t)BB * FF * sizeof(u16));
    u16*   Wp_b  = (u16*)  alloc((size_t)FF * FF * sizeof(u16));
    u16*   Wih_b = (u16*)  alloc((size_t)3 * FF * FF * sizeof(u16));
    u16*   Whh_b = (u16*)  alloc((size_t)3 * FF * FF * sizeof(u16));

    k_prep<<<(PREP_TOTAL + 255) / 256, 256, 0, stream>>>(gfe, Wp, Wih, Whh, seg, start,
                                                         gfe_b, Wp_b, Wih_b, Whh_b);
    k_ctx_logit<<<BB / 4, 256, 0, stream>>>(gfe, Wl, bl, c);
    k_attn<<<BB, 256, 0, stream>>>(node, Wl, c, start, s_b);
    k_proj_mfma<<<dim3(BB / 64, FF / 64), 256, 0, stream>>>(s_b, Wp_b, bp, start, ctx_b);
    k_gru_mfma<<<dim3(BB / 64, FF / 64), 256, 0, stream>>>(ctx_b, gfe_b, Wih_b, Whh_b,
                                                           bih, bhh, gfe, out);
}